// Round 8
// baseline (474.792 us; speedup 1.0000x reference)
//
#include <hip/hip_runtime.h>
#include <hip/hip_bf16.h>
#include <hip/hip_fp16.h>

#define B_    2
#define N_    6400
#define CD_   128
#define CM_   64
#define SEG_  5
#define JSEG_ (N_ / SEG_)    // 1280
#define JT_   64
#define NJT_  (JSEG_ / JT_)  // 20
#define NIT_  50             // i-tiles of 128 per batch (flash)
#define GRID_ (NIT_ * 2 * SEG_)   // 500 blocks (<= 512 = 256 CU x 2 blocks/CU)
#define LOG2E_ 1.4426950408889634f

typedef __attribute__((ext_vector_type(8)))  short bf16x8;
typedef __attribute__((ext_vector_type(16))) float f32x16;
typedef __attribute__((ext_vector_type(2)))  __fp16 f16x2;

static __device__ __forceinline__ unsigned pack2bf(float a, float b) {
    union { float f; unsigned u; } x, y; x.f = a; y.f = b;
    return __builtin_amdgcn_perm(y.u + 0x8000u, x.u + 0x8000u, 0x07060302u);
}

static __device__ __forceinline__ unsigned cvtpk_bf16(float a, float b) {
    unsigned r;
    asm("v_cvt_pk_bf16_f32 %0, %1, %2" : "=v"(r) : "v"(a), "v"(b));
    return r;
}

// software grid barrier (graph-capture-safe; all GRID_ blocks co-resident by
// construction: LDS 64KB -> 2 blocks/CU hard cap, grid 500 <= 512 slots).
static __device__ __forceinline__ void gridbar(unsigned* bar) {
    __syncthreads();
    __threadfence();                       // release: L2 writeback (agent scope)
    if (threadIdx.x == 0) {
        __hip_atomic_fetch_add(bar, 1u, __ATOMIC_RELEASE, __HIP_MEMORY_SCOPE_AGENT);
        while (__hip_atomic_load(bar, __ATOMIC_ACQUIRE, __HIP_MEMORY_SCOPE_AGENT) < GRID_)
            __builtin_amdgcn_s_sleep(1);
    }
    __syncthreads();
    __threadfence();                       // acquire: XCD-L2 invalidate
}

// ---------------- fused: proj -> gridbar -> flash -> gridbar -> combine ----------------
__global__ __launch_bounds__(256, 2)
void fused(const float* __restrict__ zh, const float* __restrict__ zm,
           const float* __restrict__ Wq, const float* __restrict__ bq,
           const float* __restrict__ Wk, const float* __restrict__ bk,
           const float* __restrict__ Wv, const float* __restrict__ bv,
           short* __restrict__ qb, short* __restrict__ kb, short* __restrict__ vb,
           __fp16* __restrict__ Op, float* __restrict__ ml,
           const float* __restrict__ gamma, float* __restrict__ out,
           unsigned* __restrict__ bar)
{
    __shared__ __align__(16) char smem[65536];
    const int tid = threadIdx.x;

    // ================= phase A: projections (800 units over 500 blocks) =================
    {
        float* zt = (float*)smem;        // [c][i], stride 68 (34.8 KB)
        const int ig = tid & 15, og = tid >> 4;
        const int il = ig * 4;
        for (int u = blockIdx.x; u < 800; u += GRID_) {
            int ub = u;
            const int qmode = ub < 400;
            if (!qmode) ub -= 400;
            const int b  = ub / 200;
            const int r  = ub % 200;
            const int i0 = (r >> 1) * 64;
            const int o0 = (r & 1) * 64;

            if (qmode) {
                const float* zsrc = zh + (size_t)b * CD_ * N_ + i0;
#pragma unroll
                for (int rep = 0; rep < 8; ++rep) {
                    int idx = tid + rep * 256;
                    int c = idx >> 4, f = idx & 15;
                    *(float4*)&zt[c * 68 + f * 4] = *(const float4*)&zsrc[(size_t)c * N_ + f * 4];
                }
                __syncthreads();
                const float* wr0 = Wq + (size_t)(o0 + og * 4 + 0) * CD_;
                const float* wr1 = Wq + (size_t)(o0 + og * 4 + 1) * CD_;
                const float* wr2 = Wq + (size_t)(o0 + og * 4 + 2) * CD_;
                const float* wr3 = Wq + (size_t)(o0 + og * 4 + 3) * CD_;
                float acc[4][4];
#pragma unroll
                for (int oi = 0; oi < 4; ++oi) {
                    float bb = bq[o0 + og * 4 + oi];
#pragma unroll
                    for (int ri = 0; ri < 4; ++ri) acc[ri][oi] = bb;
                }
                for (int c4 = 0; c4 < 32; ++c4) {
                    float4 w0 = *(const float4*)&wr0[c4 * 4];
                    float4 w1 = *(const float4*)&wr1[c4 * 4];
                    float4 w2 = *(const float4*)&wr2[c4 * 4];
                    float4 w3 = *(const float4*)&wr3[c4 * 4];
                    float ww[4][4] = {{w0.x,w1.x,w2.x,w3.x},{w0.y,w1.y,w2.y,w3.y},
                                      {w0.z,w1.z,w2.z,w3.z},{w0.w,w1.w,w2.w,w3.w}};
#pragma unroll
                    for (int cc = 0; cc < 4; ++cc) {
                        float4 zr = *(float4*)&zt[(c4 * 4 + cc) * 68 + il];
                        float zz[4] = {zr.x, zr.y, zr.z, zr.w};
#pragma unroll
                        for (int ri = 0; ri < 4; ++ri)
#pragma unroll
                            for (int oi = 0; oi < 4; ++oi)
                                acc[ri][oi] = fmaf(zz[ri], ww[cc][oi], acc[ri][oi]);
                    }
                }
#pragma unroll
                for (int ri = 0; ri < 4; ++ri) {
                    // pre-scale by log2(e): softmax exp becomes bare v_exp_f32
                    uint2 pk = make_uint2(
                        pack2bf(acc[ri][0] * LOG2E_, acc[ri][1] * LOG2E_),
                        pack2bf(acc[ri][2] * LOG2E_, acc[ri][3] * LOG2E_));
                    *(uint2*)&qb[((size_t)b * N_ + i0 + il + ri) * CD_ + o0 + og * 4] = pk;
                }
            } else {
                const float* zsrc = zm + (size_t)b * CM_ * N_ + i0;
#pragma unroll
                for (int rep = 0; rep < 4; ++rep) {
                    int idx = tid + rep * 256;
                    int c = idx >> 4, f = idx & 15;
                    *(float4*)&zt[c * 68 + f * 4] = *(const float4*)&zsrc[(size_t)c * N_ + f * 4];
                }
                __syncthreads();
                const float* kr0 = Wk + (size_t)(o0 + og * 4 + 0) * CM_;
                const float* kr1 = Wk + (size_t)(o0 + og * 4 + 1) * CM_;
                const float* kr2 = Wk + (size_t)(o0 + og * 4 + 2) * CM_;
                const float* kr3 = Wk + (size_t)(o0 + og * 4 + 3) * CM_;
                const float* vr0 = Wv + (size_t)(o0 + og * 4 + 0) * CM_;
                const float* vr1 = Wv + (size_t)(o0 + og * 4 + 1) * CM_;
                const float* vr2 = Wv + (size_t)(o0 + og * 4 + 2) * CM_;
                const float* vr3 = Wv + (size_t)(o0 + og * 4 + 3) * CM_;
                float ak[4][4], av[4][4];
#pragma unroll
                for (int oi = 0; oi < 4; ++oi) {
                    float bk0 = bk[o0 + og * 4 + oi], bv0 = bv[o0 + og * 4 + oi];
#pragma unroll
                    for (int ri = 0; ri < 4; ++ri) { ak[ri][oi] = bk0; av[ri][oi] = bv0; }
                }
                for (int c4 = 0; c4 < 16; ++c4) {
                    float4 k0 = *(const float4*)&kr0[c4 * 4];
                    float4 k1 = *(const float4*)&kr1[c4 * 4];
                    float4 k2 = *(const float4*)&kr2[c4 * 4];
                    float4 k3 = *(const float4*)&kr3[c4 * 4];
                    float4 v0 = *(const float4*)&vr0[c4 * 4];
                    float4 v1 = *(const float4*)&vr1[c4 * 4];
                    float4 v2 = *(const float4*)&vr2[c4 * 4];
                    float4 v3 = *(const float4*)&vr3[c4 * 4];
                    float kk[4][4] = {{k0.x,k1.x,k2.x,k3.x},{k0.y,k1.y,k2.y,k3.y},
                                      {k0.z,k1.z,k2.z,k3.z},{k0.w,k1.w,k2.w,k3.w}};
                    float vv[4][4] = {{v0.x,v1.x,v2.x,v3.x},{v0.y,v1.y,v2.y,v3.y},
                                      {v0.z,v1.z,v2.z,v3.z},{v0.w,v1.w,v2.w,v3.w}};
#pragma unroll
                    for (int cc = 0; cc < 4; ++cc) {
                        float4 zr = *(float4*)&zt[(c4 * 4 + cc) * 68 + il];
                        float zz[4] = {zr.x, zr.y, zr.z, zr.w};
#pragma unroll
                        for (int ri = 0; ri < 4; ++ri)
#pragma unroll
                            for (int oi = 0; oi < 4; ++oi) {
                                ak[ri][oi] = fmaf(zz[ri], kk[cc][oi], ak[ri][oi]);
                                av[ri][oi] = fmaf(zz[ri], vv[cc][oi], av[ri][oi]);
                            }
                    }
                }
#pragma unroll
                for (int ri = 0; ri < 4; ++ri) {
                    uint2 pk = make_uint2(pack2bf(ak[ri][0], ak[ri][1]),
                                          pack2bf(ak[ri][2], ak[ri][3]));
                    *(uint2*)&kb[((size_t)b * N_ + i0 + il + ri) * CD_ + o0 + og * 4] = pk;
                }
                const size_t vbase = (size_t)b * CD_ * N_;
#pragma unroll
                for (int oi = 0; oi < 4; ++oi) {
                    uint2 pk = make_uint2(pack2bf(av[0][oi], av[1][oi]),
                                          pack2bf(av[2][oi], av[3][oi]));
                    *(uint2*)&vb[vbase + (size_t)(o0 + og * 4 + oi) * N_ + i0 + il] = pk;
                }
            }
            __syncthreads();   // zt reused by next unit
        }
    }

    gridbar(&bar[0]);

    // ================= phase B: flash =================
    {
        short* Ks0 = (short*)smem;            // 2 x 8192 shorts
        short* Vs0 = (short*)(smem + 32768);  // 2 x 8192 shorts

        const int wid   = tid >> 6;
        const int lane  = tid & 63;
        const int m5    = lane & 31;
        const int h     = lane >> 5;
        const int m15   = m5 & 15;
        const int l4r   = lane >> 4;
        const int pc    = (lane & 15) ^ l4r;

        const int vrow = lane >> 3;
        const int vc8  = (lane & 7) ^ (vrow & 7);
        const int voff = vrow * (N_ * 2) + vc8 * 16;

        const int bid = blockIdx.x;
        const int s   = bid % SEG_;
        const int bIt = bid / SEG_;
        const int b   = bIt >= NIT_ ? 1 : 0;
        const int it  = bIt - b * NIT_;
        const int i0  = it * 128;
        const int jbase = s * JSEG_;

        const short* qbp = qb + (size_t)b * N_ * CD_;
        const short* kbp = kb + (size_t)b * N_ * CD_;
        const char*  vstage = (const char*)(vb + (size_t)b * CD_ * N_) + voff;

        const int irow = i0 + wid * 32 + m5;
        bf16x8 qf[8];
#pragma unroll
        for (int kw = 0; kw < 8; ++kw)
            qf[kw] = *(const bf16x8*)&qbp[(size_t)irow * CD_ + kw * 16 + h * 8];

        f32x16 acc[4];
#pragma unroll
        for (int os = 0; os < 4; ++os)
#pragma unroll
            for (int r2 = 0; r2 < 16; ++r2) acc[os][r2] = 0.f;
        float lrun = 0.f;

#pragma unroll
        for (int tt = 0; tt < 4; ++tt) {
            int t = wid * 4 + tt;
            int st = (4 * t) & 15;
            const char* g = (const char*)kbp + (size_t)(jbase + 4 * t + l4r) * 256
                            + ((pc ^ st) << 4);
            __builtin_amdgcn_global_load_lds(
                (const __attribute__((address_space(1))) void*)g,
                (__attribute__((address_space(3))) void*)(Ks0 + t * 512), 16, 0, 0);
        }
#pragma unroll
        for (int tt = 0; tt < 4; ++tt) {
            int t = wid * 4 + tt;
            const char* g = vstage + (size_t)(t * 8) * (N_ * 2) + (size_t)jbase * 2;
            __builtin_amdgcn_global_load_lds(
                (const __attribute__((address_space(1))) void*)g,
                (__attribute__((address_space(3))) void*)(Vs0 + t * 512), 16, 0, 0);
        }
        __syncthreads();

        for (int jti = 0; jti < NJT_; ++jti) {
            const int jt  = jbase + jti * JT_;
            const int cur = jti & 1;
            if (jti + 1 < NJT_) {
                const int jn = jt + JT_;
#pragma unroll
                for (int tt = 0; tt < 4; ++tt) {
                    int t = wid * 4 + tt;
                    int st = (4 * t) & 15;
                    const char* g = (const char*)kbp + (size_t)(jn + 4 * t + l4r) * 256
                                    + ((pc ^ st) << 4);
                    __builtin_amdgcn_global_load_lds(
                        (const __attribute__((address_space(1))) void*)g,
                        (__attribute__((address_space(3))) void*)(Ks0 + (1 - cur) * 8192 + t * 512), 16, 0, 0);
                }
#pragma unroll
                for (int tt = 0; tt < 4; ++tt) {
                    int t = wid * 4 + tt;
                    const char* g = vstage + (size_t)(t * 8) * (N_ * 2) + (size_t)jn * 2;
                    __builtin_amdgcn_global_load_lds(
                        (const __attribute__((address_space(1))) void*)g,
                        (__attribute__((address_space(3))) void*)(Vs0 + (1 - cur) * 8192 + t * 512), 16, 0, 0);
                }
            }

            unsigned fr[4][4];
#pragma unroll
            for (int jc = 0; jc < 2; ++jc) {
                // QK^T; C-init = -25*log2e so P = exp2(sacc) directly
                f32x16 sacc;
#pragma unroll
                for (int r2 = 0; r2 < 16; ++r2) sacc[r2] = -36.067376022224085f;
                __builtin_amdgcn_s_setprio(1);
#pragma unroll
                for (int kw = 0; kw < 8; ++kw) {
                    int c16 = (2 * kw + h) ^ m15;
                    bf16x8 kf = *(const bf16x8*)&Ks0[cur * 8192 + (jc * 32 + m5) * 128 + c16 * 8];
                    sacc = __builtin_amdgcn_mfma_f32_32x32x16_bf16(kf, qf[kw], sacc, 0, 0, 0);
                }
                __builtin_amdgcn_s_setprio(0);
                unsigned pk[8];
#pragma unroll
                for (int p = 0; p < 8; ++p) {
                    float e0 = exp2f(sacc[2 * p]);
                    float e1 = exp2f(sacc[2 * p + 1]);
                    lrun += e0 + e1;
                    pk[p] = cvtpk_bf16(e0, e1);
                }
#pragma unroll
                for (int X = 0; X < 2; ++X) {
                    auto r0 = __builtin_amdgcn_permlane32_swap(
                                  pk[4 * X],     pk[4 * X + 2], false, false);
                    auto r1 = __builtin_amdgcn_permlane32_swap(
                                  pk[4 * X + 1], pk[4 * X + 3], false, false);
                    fr[2 * jc + X][0] = (unsigned)r0[0];
                    fr[2 * jc + X][1] = (unsigned)r1[0];
                    fr[2 * jc + X][2] = (unsigned)r0[1];
                    fr[2 * jc + X][3] = (unsigned)r1[1];
                }
            }
            __builtin_amdgcn_s_setprio(1);
#pragma unroll
            for (int kc = 0; kc < 4; ++kc) {
                union { unsigned u[4]; bf16x8 v; } pf;
#pragma unroll
                for (int u = 0; u < 4; ++u) pf.u[u] = fr[kc][u];
#pragma unroll
                for (int os = 0; os < 4; ++os) {
                    int o = os * 32 + m5;
                    int q = (kc * 2 + h) ^ (m5 & 7);
                    bf16x8 vf = *(const bf16x8*)&Vs0[cur * 8192 + o * 64 + q * 8];
                    acc[os] = __builtin_amdgcn_mfma_f32_32x32x16_bf16(vf, pf.v, acc[os], 0, 0, 0);
                }
            }
            __builtin_amdgcn_s_setprio(0);
            __syncthreads();
        }

        float lt = lrun + __shfl_xor(lrun, 32);
        if (h == 0) ml[((size_t)bIt * SEG_ + s) * 128 + wid * 32 + m5] = lt;
        const float linv = 1.0f / lt;

        float* Of = (float*)smem;          // 32 KB
        __fp16* opb = Op + ((size_t)bIt * SEG_ + s) * (128 * CD_);
#pragma unroll
        for (int r = 0; r < 2; ++r) {
            __syncthreads();
            if ((wid >> 1) == r) {
                const int il_ = (wid & 1) * 32 + m5;
#pragma unroll
                for (int os = 0; os < 4; ++os) {
#pragma unroll
                    for (int g = 0; g < 4; ++g) {
                        int q = os * 8 + g * 2 + h;
                        int p = q ^ m5;
                        *(float4*)&Of[il_ * 128 + p * 4] =
                            make_float4(acc[os][4 * g] * linv, acc[os][4 * g + 1] * linv,
                                        acc[os][4 * g + 2] * linv, acc[os][4 * g + 3] * linv);
                    }
                }
            }
            __syncthreads();
#pragma unroll
            for (int u = 0; u < 8; ++u) {
                int G = u * 256 + tid;
                int i = G >> 5;
                int q = tid & 31;
                int p = q ^ (i & 31);
                float4 t = *(float4*)&Of[i * 128 + p * 4];
                union { f16x2 h2[2]; uint2 u2; } cv;
                cv.h2[0] = __builtin_amdgcn_cvt_pkrtz(t.x, t.y);
                cv.h2[1] = __builtin_amdgcn_cvt_pkrtz(t.z, t.w);
                *(uint2*)&opb[(size_t)r * 64 * CD_ + (size_t)G * 4] = cv.u2;
            }
        }
    }

    gridbar(&bar[1]);

    // ================= phase C: combine (400 units) =================
    if (blockIdx.x < 400) {
        float* T = (float*)smem;                       // 128*36 f32 = 18432 B
        float (*wbuf)[32] = (float(*)[32])(smem + 18944);
        const int blk = blockIdx.x;
        const int bIt = blk >> 2;
        const int rq  = (blk & 3) * 32;
        const int b   = bIt / NIT_;
        const int it  = bIt % NIT_;
        const int i0  = it * 128 + rq;
        const float g = gamma[0];

        if (tid < 32) {
            float l[SEG_];
            float den = 0.f;
#pragma unroll
            for (int s2 = 0; s2 < SEG_; ++s2) {
                l[s2] = ml[((size_t)bIt * SEG_ + s2) * 128 + rq + tid];
                den += l[s2];
            }
            const float gd = g / den;
#pragma unroll
            for (int s2 = 0; s2 < SEG_; ++s2)
                wbuf[s2][tid] = l[s2] * gd;
        }
        __syncthreads();
        {
            const int i  = tid >> 3;
            const int oc = (tid & 7) * 4;
            float w[SEG_];
#pragma unroll
            for (int s2 = 0; s2 < SEG_; ++s2) w[s2] = wbuf[s2][i];
            const __fp16* base = Op + ((size_t)bIt * SEG_ * 128 + rq + i) * CD_ + oc;
#pragma unroll
            for (int c4 = 0; c4 < 4; ++c4) {
                float ax = 0.f, ay = 0.f, az = 0.f, aw = 0.f;
#pragma unroll
                for (int s2 = 0; s2 < SEG_; ++s2) {
                    union { uint2 u2; f16x2 h2[2]; } raw;
                    raw.u2 = *(const uint2*)&base[(size_t)s2 * 128 * CD_ + c4 * 32];
                    ax = fmaf((float)raw.h2[0][0], w[s2], ax);
                    ay = fmaf((float)raw.h2[0][1], w[s2], ay);
                    az = fmaf((float)raw.h2[1][0], w[s2], az);
                    aw = fmaf((float)raw.h2[1][1], w[s2], aw);
                }
                int o = oc + c4 * 32;
                T[(o + 0) * 36 + i] = ax;
                T[(o + 1) * 36 + i] = ay;
                T[(o + 2) * 36 + i] = az;
                T[(o + 3) * 36 + i] = aw;
            }
        }
        __syncthreads();
        {
            const int o = tid >> 1, ih = (tid & 1) * 16;
            const size_t gbase = ((size_t)b * CD_ + o) * N_ + i0 + ih;
#pragma unroll
            for (int rr = 0; rr < 4; ++rr) {
                float4 t  = *(float4*)&T[o * 36 + ih + rr * 4];
                float4 z4 = *(const float4*)&zh[gbase + rr * 4];
                *(float4*)&out[gbase + rr * 4] =
                    make_float4(t.x + z4.x, t.y + z4.y, t.z + z4.z, t.w + z4.w);
            }
        }
    }
}

extern "C" void kernel_launch(void* const* d_in, const int* in_sizes, int n_in,
                              void* d_out, int out_size, void* d_ws, size_t ws_size,
                              hipStream_t stream) {
    const float* z_hsi = (const float*)d_in[0];
    const float* z_msi = (const float*)d_in[1];
    const float* Wq    = (const float*)d_in[2];
    const float* bq    = (const float*)d_in[3];
    const float* Wk    = (const float*)d_in[4];
    const float* bk    = (const float*)d_in[5];
    const float* Wv    = (const float*)d_in[6];
    const float* bv    = (const float*)d_in[7];
    const float* gamma = (const float*)d_in[8];
    float* out = (float*)d_out;

    const size_t nqb = (size_t)B_ * N_ * CD_;
    short* qb = (short*)d_ws;
    short* kb = qb + nqb;
    short* vb = kb + nqb;
    __fp16* Op = (__fp16*)(vb + nqb);                  // 16.4 MB
    float* ml = (float*)(Op + (size_t)100 * SEG_ * 128 * CD_);
    unsigned* bar = (unsigned*)(ml + (size_t)100 * SEG_ * 128);

    hipMemsetAsync(bar, 0, 2 * sizeof(unsigned), stream);
    fused<<<dim3(GRID_), dim3(256), 0, stream>>>(
        z_hsi, z_msi, Wq, bq, Wk, bk, Wv, bv,
        qb, kb, vb, Op, ml, gamma, out, bar);
}

// Round 9
// 224.321 us; speedup vs baseline: 2.1166x; 2.1166x over previous
//
#include <hip/hip_runtime.h>
#include <hip/hip_bf16.h>
#include <hip/hip_fp16.h>

#define B_    2
#define N_    6400
#define CD_   128
#define CM_   64
#define SEG_  5
#define JSEG_ (N_ / SEG_)    // 1280
#define JT_   64
#define NJT_  (JSEG_ / JT_)  // 20
#define NIT_  50             // i-tiles of 128 per batch (flash)
#define LOG2E_ 1.4426950408889634f

typedef __attribute__((ext_vector_type(8)))  short bf16x8;
typedef __attribute__((ext_vector_type(16))) float f32x16;
typedef __attribute__((ext_vector_type(2)))  __fp16 f16x2;

static __device__ __forceinline__ unsigned pack2bf(float a, float b) {
    union { float f; unsigned u; } x, y; x.f = a; y.f = b;
    return __builtin_amdgcn_perm(y.u + 0x8000u, x.u + 0x8000u, 0x07060302u);
}

static __device__ __forceinline__ unsigned cvtpk_bf16(float a, float b) {
    unsigned r;
    asm("v_cvt_pk_bf16_f32 %0, %1, %2" : "=v"(r) : "v"(a), "v"(b));
    return r;
}

// ---------------- fused projections ----------------
// blocks [0,400): q from z_hsi (C=128), PRE-SCALED by log2(e); [400,800): k,v.
// block 0 also zeroes the fan-in tile counters for the flash kernel.
__global__ __launch_bounds__(256, 4)
void proj2(const float* __restrict__ zh, const float* __restrict__ zm,
           const float* __restrict__ Wq, const float* __restrict__ bq,
           const float* __restrict__ Wk, const float* __restrict__ bk,
           const float* __restrict__ Wv, const float* __restrict__ bv,
           short* __restrict__ qb, short* __restrict__ kb, short* __restrict__ vb,
           unsigned* __restrict__ tilecnt)
{
    __shared__ float zt[128 * 68];   // [c][i], stride 68 (16B-aligned rows)
    const int tid = threadIdx.x;
    int bid = blockIdx.x;
    if (bid == 0 && tid < 100) tilecnt[tid] = 0;   // visible to flash at kernel boundary
    const int qmode = bid < 400;
    if (!qmode) bid -= 400;
    const int b  = bid / 200;
    const int r  = bid % 200;
    const int i0 = (r >> 1) * 64;
    const int o0 = (r & 1) * 64;
    const int ig = tid & 15, og = tid >> 4;
    const int il = ig * 4;

    if (qmode) {
        const float* zsrc = zh + (size_t)b * CD_ * N_ + i0;
#pragma unroll
        for (int rep = 0; rep < 8; ++rep) {
            int idx = tid + rep * 256;
            int c = idx >> 4, f = idx & 15;
            *(float4*)&zt[c * 68 + f * 4] = *(const float4*)&zsrc[(size_t)c * N_ + f * 4];
        }
        __syncthreads();
        const float* wr0 = Wq + (size_t)(o0 + og * 4 + 0) * CD_;
        const float* wr1 = Wq + (size_t)(o0 + og * 4 + 1) * CD_;
        const float* wr2 = Wq + (size_t)(o0 + og * 4 + 2) * CD_;
        const float* wr3 = Wq + (size_t)(o0 + og * 4 + 3) * CD_;
        float acc[4][4];
#pragma unroll
        for (int oi = 0; oi < 4; ++oi) {
            float bb = bq[o0 + og * 4 + oi];
#pragma unroll
            for (int ri = 0; ri < 4; ++ri) acc[ri][oi] = bb;
        }
        for (int c4 = 0; c4 < 32; ++c4) {
            float4 w0 = *(const float4*)&wr0[c4 * 4];
            float4 w1 = *(const float4*)&wr1[c4 * 4];
            float4 w2 = *(const float4*)&wr2[c4 * 4];
            float4 w3 = *(const float4*)&wr3[c4 * 4];
            float ww[4][4] = {{w0.x,w1.x,w2.x,w3.x},{w0.y,w1.y,w2.y,w3.y},
                              {w0.z,w1.z,w2.z,w3.z},{w0.w,w1.w,w2.w,w3.w}};
#pragma unroll
            for (int cc = 0; cc < 4; ++cc) {
                float4 zr = *(float4*)&zt[(c4 * 4 + cc) * 68 + il];
                float zz[4] = {zr.x, zr.y, zr.z, zr.w};
#pragma unroll
                for (int ri = 0; ri < 4; ++ri)
#pragma unroll
                    for (int oi = 0; oi < 4; ++oi)
                        acc[ri][oi] = fmaf(zz[ri], ww[cc][oi], acc[ri][oi]);
            }
        }
#pragma unroll
        for (int ri = 0; ri < 4; ++ri) {
            uint2 pk = make_uint2(
                pack2bf(acc[ri][0] * LOG2E_, acc[ri][1] * LOG2E_),
                pack2bf(acc[ri][2] * LOG2E_, acc[ri][3] * LOG2E_));
            *(uint2*)&qb[((size_t)b * N_ + i0 + il + ri) * CD_ + o0 + og * 4] = pk;
        }
    } else {
        const float* zsrc = zm + (size_t)b * CM_ * N_ + i0;
#pragma unroll
        for (int rep = 0; rep < 4; ++rep) {
            int idx = tid + rep * 256;
            int c = idx >> 4, f = idx & 15;
            *(float4*)&zt[c * 68 + f * 4] = *(const float4*)&zsrc[(size_t)c * N_ + f * 4];
        }
        __syncthreads();
        const float* kr0 = Wk + (size_t)(o0 + og * 4 + 0) * CM_;
        const float* kr1 = Wk + (size_t)(o0 + og * 4 + 1) * CM_;
        const float* kr2 = Wk + (size_t)(o0 + og * 4 + 2) * CM_;
        const float* kr3 = Wk + (size_t)(o0 + og * 4 + 3) * CM_;
        const float* vr0 = Wv + (size_t)(o0 + og * 4 + 0) * CM_;
        const float* vr1 = Wv + (size_t)(o0 + og * 4 + 1) * CM_;
        const float* vr2 = Wv + (size_t)(o0 + og * 4 + 2) * CM_;
        const float* vr3 = Wv + (size_t)(o0 + og * 4 + 3) * CM_;
        float ak[4][4], av[4][4];
#pragma unroll
        for (int oi = 0; oi < 4; ++oi) {
            float bk0 = bk[o0 + og * 4 + oi], bv0 = bv[o0 + og * 4 + oi];
#pragma unroll
            for (int ri = 0; ri < 4; ++ri) { ak[ri][oi] = bk0; av[ri][oi] = bv0; }
        }
        for (int c4 = 0; c4 < 16; ++c4) {
            float4 k0 = *(const float4*)&kr0[c4 * 4];
            float4 k1 = *(const float4*)&kr1[c4 * 4];
            float4 k2 = *(const float4*)&kr2[c4 * 4];
            float4 k3 = *(const float4*)&kr3[c4 * 4];
            float4 v0 = *(const float4*)&vr0[c4 * 4];
            float4 v1 = *(const float4*)&vr1[c4 * 4];
            float4 v2 = *(const float4*)&vr2[c4 * 4];
            float4 v3 = *(const float4*)&vr3[c4 * 4];
            float kk[4][4] = {{k0.x,k1.x,k2.x,k3.x},{k0.y,k1.y,k2.y,k3.y},
                              {k0.z,k1.z,k2.z,k3.z},{k0.w,k1.w,k2.w,k3.w}};
            float vv[4][4] = {{v0.x,v1.x,v2.x,v3.x},{v0.y,v1.y,v2.y,v3.y},
                              {v0.z,v1.z,v2.z,v3.z},{v0.w,v1.w,v2.w,v3.w}};
#pragma unroll
            for (int cc = 0; cc < 4; ++cc) {
                float4 zr = *(float4*)&zt[(c4 * 4 + cc) * 68 + il];
                float zz[4] = {zr.x, zr.y, zr.z, zr.w};
#pragma unroll
                for (int ri = 0; ri < 4; ++ri)
#pragma unroll
                    for (int oi = 0; oi < 4; ++oi) {
                        ak[ri][oi] = fmaf(zz[ri], kk[cc][oi], ak[ri][oi]);
                        av[ri][oi] = fmaf(zz[ri], vv[cc][oi], av[ri][oi]);
                    }
            }
        }
#pragma unroll
        for (int ri = 0; ri < 4; ++ri) {
            uint2 pk = make_uint2(pack2bf(ak[ri][0], ak[ri][1]),
                                  pack2bf(ak[ri][2], ak[ri][3]));
            *(uint2*)&kb[((size_t)b * N_ + i0 + il + ri) * CD_ + o0 + og * 4] = pk;
        }
        const size_t vbase = (size_t)b * CD_ * N_;
#pragma unroll
        for (int oi = 0; oi < 4; ++oi) {
            uint2 pk = make_uint2(pack2bf(av[0][oi], av[1][oi]),
                                  pack2bf(av[2][oi], av[3][oi]));
            *(uint2*)&vb[vbase + (size_t)(o0 + og * 4 + oi) * N_ + i0 + il] = pk;
        }
    }
}

// ---------------- flash + wait-free fan-in combine ----------------
// As R6's flash6 (K/V LDS dbuf, f16 normalized partials) plus:
//  - exp2 softmax (q pre-scaled; C-init = -25*log2e)
//  - last-arriving segment block of each i-tile combines (atomic fan-in,
//    device-scope; no spinning, no co-residency assumption)
__global__ __launch_bounds__(256, 2)
void flash7(const short* __restrict__ qb, const short* __restrict__ kb,
            const short* __restrict__ vb, __fp16* __restrict__ Op,
            float* __restrict__ ml, unsigned* __restrict__ tilecnt,
            const float* __restrict__ zh, const float* __restrict__ gamma,
            float* __restrict__ out)
{
    __shared__ __align__(16) char smem[65536];
    __shared__ unsigned oldc_sh;
    short* Ks0 = (short*)smem;            // 2 x 8192 shorts
    short* Vs0 = (short*)(smem + 32768);  // 2 x 8192 shorts

    const int tid   = threadIdx.x;
    const int wid   = tid >> 6;
    const int lane  = tid & 63;
    const int m5    = lane & 31;
    const int h     = lane >> 5;
    const int m15   = m5 & 15;
    const int l4r   = lane >> 4;
    const int pc    = (lane & 15) ^ l4r;

    const int vrow = lane >> 3;
    const int vc8  = (lane & 7) ^ (vrow & 7);
    const int voff = vrow * (N_ * 2) + vc8 * 16;

    const int bid = blockIdx.x;
    const int s   = bid % SEG_;
    const int bIt = bid / SEG_;
    const int b   = bIt >= NIT_ ? 1 : 0;
    const int it  = bIt - b * NIT_;
    const int i0  = it * 128;
    const int jbase = s * JSEG_;

    const short* qbp = qb + (size_t)b * N_ * CD_;
    const short* kbp = kb + (size_t)b * N_ * CD_;
    const char*  vstage = (const char*)(vb + (size_t)b * CD_ * N_) + voff;

    const int irow = i0 + wid * 32 + m5;
    bf16x8 qf[8];
#pragma unroll
    for (int kw = 0; kw < 8; ++kw)
        qf[kw] = *(const bf16x8*)&qbp[(size_t)irow * CD_ + kw * 16 + h * 8];

    f32x16 acc[4];
#pragma unroll
    for (int os = 0; os < 4; ++os)
#pragma unroll
        for (int r2 = 0; r2 < 16; ++r2) acc[os][r2] = 0.f;
    float lrun = 0.f;

#pragma unroll
    for (int tt = 0; tt < 4; ++tt) {
        int t = wid * 4 + tt;
        int st = (4 * t) & 15;
        const char* g = (const char*)kbp + (size_t)(jbase + 4 * t + l4r) * 256
                        + ((pc ^ st) << 4);
        __builtin_amdgcn_global_load_lds(
            (const __attribute__((address_space(1))) void*)g,
            (__attribute__((address_space(3))) void*)(Ks0 + t * 512), 16, 0, 0);
    }
#pragma unroll
    for (int tt = 0; tt < 4; ++tt) {
        int t = wid * 4 + tt;
        const char* g = vstage + (size_t)(t * 8) * (N_ * 2) + (size_t)jbase * 2;
        __builtin_amdgcn_global_load_lds(
            (const __attribute__((address_space(1))) void*)g,
            (__attribute__((address_space(3))) void*)(Vs0 + t * 512), 16, 0, 0);
    }
    __syncthreads();

    for (int jti = 0; jti < NJT_; ++jti) {
        const int jt  = jbase + jti * JT_;
        const int cur = jti & 1;
        if (jti + 1 < NJT_) {
            const int jn = jt + JT_;
#pragma unroll
            for (int tt = 0; tt < 4; ++tt) {
                int t = wid * 4 + tt;
                int st = (4 * t) & 15;
                const char* g = (const char*)kbp + (size_t)(jn + 4 * t + l4r) * 256
                                + ((pc ^ st) << 4);
                __builtin_amdgcn_global_load_lds(
                    (const __attribute__((address_space(1))) void*)g,
                    (__attribute__((address_space(3))) void*)(Ks0 + (1 - cur) * 8192 + t * 512), 16, 0, 0);
            }
#pragma unroll
            for (int tt = 0; tt < 4; ++tt) {
                int t = wid * 4 + tt;
                const char* g = vstage + (size_t)(t * 8) * (N_ * 2) + (size_t)jn * 2;
                __builtin_amdgcn_global_load_lds(
                    (const __attribute__((address_space(1))) void*)g,
                    (__attribute__((address_space(3))) void*)(Vs0 + (1 - cur) * 8192 + t * 512), 16, 0, 0);
            }
        }

        unsigned fr[4][4];
#pragma unroll
        for (int jc = 0; jc < 2; ++jc) {
            // QK^T; C-init = -25*log2e so P = exp2(sacc) directly
            f32x16 sacc;
#pragma unroll
            for (int r2 = 0; r2 < 16; ++r2) sacc[r2] = -36.067376022224085f;
            __builtin_amdgcn_s_setprio(1);
#pragma unroll
            for (int kw = 0; kw < 8; ++kw) {
                int c16 = (2 * kw + h) ^ m15;
                bf16x8 kf = *(const bf16x8*)&Ks0[cur * 8192 + (jc * 32 + m5) * 128 + c16 * 8];
                sacc = __builtin_amdgcn_mfma_f32_32x32x16_bf16(kf, qf[kw], sacc, 0, 0, 0);
            }
            __builtin_amdgcn_s_setprio(0);
            unsigned pk[8];
#pragma unroll
            for (int p = 0; p < 8; ++p) {
                float e0 = exp2f(sacc[2 * p]);
                float e1 = exp2f(sacc[2 * p + 1]);
                lrun += e0 + e1;
                pk[p] = cvtpk_bf16(e0, e1);
            }
#pragma unroll
            for (int X = 0; X < 2; ++X) {
                auto r0 = __builtin_amdgcn_permlane32_swap(
                              pk[4 * X],     pk[4 * X + 2], false, false);
                auto r1 = __builtin_amdgcn_permlane32_swap(
                              pk[4 * X + 1], pk[4 * X + 3], false, false);
                fr[2 * jc + X][0] = (unsigned)r0[0];
                fr[2 * jc + X][1] = (unsigned)r1[0];
                fr[2 * jc + X][2] = (unsigned)r0[1];
                fr[2 * jc + X][3] = (unsigned)r1[1];
            }
        }
        __builtin_amdgcn_s_setprio(1);
#pragma unroll
        for (int kc = 0; kc < 4; ++kc) {
            union { unsigned u[4]; bf16x8 v; } pf;
#pragma unroll
            for (int u = 0; u < 4; ++u) pf.u[u] = fr[kc][u];
#pragma unroll
            for (int os = 0; os < 4; ++os) {
                int o = os * 32 + m5;
                int q = (kc * 2 + h) ^ (m5 & 7);
                bf16x8 vf = *(const bf16x8*)&Vs0[cur * 8192 + o * 64 + q * 8];
                acc[os] = __builtin_amdgcn_mfma_f32_32x32x16_bf16(vf, pf.v, acc[os], 0, 0, 0);
            }
        }
        __builtin_amdgcn_s_setprio(0);
        __syncthreads();
    }

    float lt = lrun + __shfl_xor(lrun, 32);
    if (h == 0) ml[((size_t)bIt * SEG_ + s) * 128 + wid * 32 + m5] = lt;
    const float linv = 1.0f / lt;

    // epilogue: normalized partials -> f16 Op
    float* Of = (float*)smem;
    __fp16* opb = Op + ((size_t)bIt * SEG_ + s) * (128 * CD_);
#pragma unroll
    for (int r = 0; r < 2; ++r) {
        __syncthreads();
        if ((wid >> 1) == r) {
            const int il_ = (wid & 1) * 32 + m5;
#pragma unroll
            for (int os = 0; os < 4; ++os) {
#pragma unroll
                for (int g = 0; g < 4; ++g) {
                    int q = os * 8 + g * 2 + h;
                    int p = q ^ m5;
                    *(float4*)&Of[il_ * 128 + p * 4] =
                        make_float4(acc[os][4 * g] * linv, acc[os][4 * g + 1] * linv,
                                    acc[os][4 * g + 2] * linv, acc[os][4 * g + 3] * linv);
                }
            }
        }
        __syncthreads();
#pragma unroll
        for (int u = 0; u < 8; ++u) {
            int G = u * 256 + tid;
            int i = G >> 5;
            int q = tid & 31;
            int p = q ^ (i & 31);
            float4 t = *(float4*)&Of[i * 128 + p * 4];
            union { f16x2 h2[2]; uint2 u2; } cv;
            cv.h2[0] = __builtin_amdgcn_cvt_pkrtz(t.x, t.y);
            cv.h2[1] = __builtin_amdgcn_cvt_pkrtz(t.z, t.w);
            *(uint2*)&opb[(size_t)r * 64 * CD_ + (size_t)G * 4] = cv.u2;
        }
    }

    // -------- wait-free fan-in: last of the 5 segment-blocks combines --------
    __syncthreads();
    if (tid == 0) {
        __threadfence();                                   // release Op/ml
        oldc_sh = __hip_atomic_fetch_add(&tilecnt[bIt], 1u,
                                         __ATOMIC_ACQ_REL, __HIP_MEMORY_SCOPE_AGENT);
    }
    __syncthreads();
    if (oldc_sh == SEG_ - 1) {
        __threadfence();                                   // acquire others' Op/ml
        float* T = (float*)smem;                           // [o][i(64)+pad], 34.8 KB
        const float g = gamma[0];
        const __fp16* opt = Op + (size_t)bIt * SEG_ * (128 * CD_);
#pragma unroll
        for (int r = 0; r < 2; ++r) {
            const int i   = tid >> 2;                      // 0..63
            const int row = r * 64 + i;
            float l[SEG_], den = 0.f;
#pragma unroll
            for (int s2 = 0; s2 < SEG_; ++s2) {
                l[s2] = ml[((size_t)bIt * SEG_ + s2) * 128 + row];
                den += l[s2];
            }
            const float gd = g / den;
            float w[SEG_];
#pragma unroll
            for (int s2 = 0; s2 < SEG_; ++s2) w[s2] = l[s2] * gd;
            const int oc = (tid & 3) * 32;
#pragma unroll
            for (int och = 0; och < 8; ++och) {
                int o4 = oc + och * 4;
                float ax = 0.f, ay = 0.f, az = 0.f, aw = 0.f;
#pragma unroll
                for (int s2 = 0; s2 < SEG_; ++s2) {
                    union { uint2 u2; f16x2 h2[2]; } raw;
                    raw.u2 = *(const uint2*)&opt[((size_t)s2 * 128 + row) * CD_ + o4];
                    ax = fmaf((float)raw.h2[0][0], w[s2], ax);
                    ay = fmaf((float)raw.h2[0][1], w[s2], ay);
                    az = fmaf((float)raw.h2[1][0], w[s2], az);
                    aw = fmaf((float)raw.h2[1][1], w[s2], aw);
                }
                T[(o4 + 0) * 68 + i] = ax;
                T[(o4 + 1) * 68 + i] = ay;
                T[(o4 + 2) * 68 + i] = az;
                T[(o4 + 3) * 68 + i] = aw;
            }
            __syncthreads();
            {
                const int o = tid >> 1, ih = (tid & 1) * 32;
                const size_t gbase = ((size_t)b * CD_ + o) * N_ + i0 + r * 64 + ih;
#pragma unroll
                for (int rr = 0; rr < 8; ++rr) {
                    float4 t  = *(float4*)&T[o * 68 + ih + rr * 4];
                    float4 z4 = *(const float4*)&zh[gbase + rr * 4];
                    *(float4*)&out[gbase + rr * 4] =
                        make_float4(t.x + z4.x, t.y + z4.y, t.z + z4.z, t.w + z4.w);
                }
            }
            __syncthreads();
        }
    }
}

extern "C" void kernel_launch(void* const* d_in, const int* in_sizes, int n_in,
                              void* d_out, int out_size, void* d_ws, size_t ws_size,
                              hipStream_t stream) {
    const float* z_hsi = (const float*)d_in[0];
    const float* z_msi = (const float*)d_in[1];
    const float* Wq    = (const float*)d_in[2];
    const float* bq    = (const float*)d_in[3];
    const float* Wk    = (const float*)d_in[4];
    const float* bk    = (const float*)d_in[5];
    const float* Wv    = (const float*)d_in[6];
    const float* bv    = (const float*)d_in[7];
    const float* gamma = (const float*)d_in[8];
    float* out = (float*)d_out;

    const size_t nqb = (size_t)B_ * N_ * CD_;
    short* qb = (short*)d_ws;
    short* kb = qb + nqb;
    short* vb = kb + nqb;
    __fp16* Op = (__fp16*)(vb + nqb);                              // 16.4 MB
    float* ml = (float*)(Op + (size_t)100 * SEG_ * 128 * CD_);     // 256 KB
    unsigned* tilecnt = (unsigned*)(ml + (size_t)100 * SEG_ * 128);

    proj2<<<dim3(800), dim3(256), 0, stream>>>(z_hsi, z_msi, Wq, bq, Wk, bk, Wv, bv,
                                               qb, kb, vb, tilecnt);
    flash7<<<dim3(100 * SEG_), dim3(256), 0, stream>>>(qb, kb, vb, Op, ml, tilecnt,
                                                       z_hsi, gamma, out);
}

// Round 10
// 171.262 us; speedup vs baseline: 2.7723x; 1.3098x over previous
//
#include <hip/hip_runtime.h>
#include <hip/hip_bf16.h>
#include <hip/hip_fp16.h>

#define B_    2
#define N_    6400
#define CD_   128
#define CM_   64
#define SEG_  5
#define JSEG_ (N_ / SEG_)    // 1280
#define JT_   64
#define NJT_  (JSEG_ / JT_)  // 20
#define NIT_  50             // i-tiles of 128 per batch (flash)
#define LOG2E_ 1.4426950408889634f

typedef __attribute__((ext_vector_type(8)))  short bf16x8;
typedef __attribute__((ext_vector_type(16))) float f32x16;
typedef __attribute__((ext_vector_type(2)))  __fp16 f16x2;
typedef unsigned long long u64;

static __device__ __forceinline__ unsigned pack2bf(float a, float b) {
    union { float f; unsigned u; } x, y; x.f = a; y.f = b;
    return __builtin_amdgcn_perm(y.u + 0x8000u, x.u + 0x8000u, 0x07060302u);
}

static __device__ __forceinline__ unsigned cvtpk_bf16(float a, float b) {
    unsigned r;
    asm("v_cvt_pk_bf16_f32 %0, %1, %2" : "=v"(r) : "v"(a), "v"(b));
    return r;
}

// agent-scope (sc0 sc1) write-through store / LLC load — cross-XCD visibility
// WITHOUT L2 writeback/invalidate fences (the R9 regression).
static __device__ __forceinline__ void st_agent(u64* p, u64 v) {
    __hip_atomic_store(p, v, __ATOMIC_RELAXED, __HIP_MEMORY_SCOPE_AGENT);
}
static __device__ __forceinline__ u64 ld_agent(const u64* p) {
    return __hip_atomic_load(p, __ATOMIC_RELAXED, __HIP_MEMORY_SCOPE_AGENT);
}
static __device__ __forceinline__ void st_agent_f(float* p, float v) {
    __hip_atomic_store(p, v, __ATOMIC_RELAXED, __HIP_MEMORY_SCOPE_AGENT);
}
static __device__ __forceinline__ float ld_agent_f(const float* p) {
    return __hip_atomic_load(p, __ATOMIC_RELAXED, __HIP_MEMORY_SCOPE_AGENT);
}

// ---------------- fused projections ----------------
// blocks [0,400): q from z_hsi (C=128), PRE-SCALED by log2(e); [400,800): k,v.
// block 0 zeroes the fan-in tile counters (agent store -> at LLC immediately).
__global__ __launch_bounds__(256, 4)
void proj2(const float* __restrict__ zh, const float* __restrict__ zm,
           const float* __restrict__ Wq, const float* __restrict__ bq,
           const float* __restrict__ Wk, const float* __restrict__ bk,
           const float* __restrict__ Wv, const float* __restrict__ bv,
           short* __restrict__ qb, short* __restrict__ kb, short* __restrict__ vb,
           unsigned* __restrict__ tilecnt)
{
    __shared__ float zt[128 * 68];   // [c][i], stride 68 (16B-aligned rows)
    const int tid = threadIdx.x;
    int bid = blockIdx.x;
    if (bid == 0 && tid < 100)
        __hip_atomic_store(&tilecnt[tid], 0u, __ATOMIC_RELAXED, __HIP_MEMORY_SCOPE_AGENT);
    const int qmode = bid < 400;
    if (!qmode) bid -= 400;
    const int b  = bid / 200;
    const int r  = bid % 200;
    const int i0 = (r >> 1) * 64;
    const int o0 = (r & 1) * 64;
    const int ig = tid & 15, og = tid >> 4;
    const int il = ig * 4;

    if (qmode) {
        const float* zsrc = zh + (size_t)b * CD_ * N_ + i0;
#pragma unroll
        for (int rep = 0; rep < 8; ++rep) {
            int idx = tid + rep * 256;
            int c = idx >> 4, f = idx & 15;
            *(float4*)&zt[c * 68 + f * 4] = *(const float4*)&zsrc[(size_t)c * N_ + f * 4];
        }
        __syncthreads();
        const float* wr0 = Wq + (size_t)(o0 + og * 4 + 0) * CD_;
        const float* wr1 = Wq + (size_t)(o0 + og * 4 + 1) * CD_;
        const float* wr2 = Wq + (size_t)(o0 + og * 4 + 2) * CD_;
        const float* wr3 = Wq + (size_t)(o0 + og * 4 + 3) * CD_;
        float acc[4][4];
#pragma unroll
        for (int oi = 0; oi < 4; ++oi) {
            float bb = bq[o0 + og * 4 + oi];
#pragma unroll
            for (int ri = 0; ri < 4; ++ri) acc[ri][oi] = bb;
        }
        for (int c4 = 0; c4 < 32; ++c4) {
            float4 w0 = *(const float4*)&wr0[c4 * 4];
            float4 w1 = *(const float4*)&wr1[c4 * 4];
            float4 w2 = *(const float4*)&wr2[c4 * 4];
            float4 w3 = *(const float4*)&wr3[c4 * 4];
            float ww[4][4] = {{w0.x,w1.x,w2.x,w3.x},{w0.y,w1.y,w2.y,w3.y},
                              {w0.z,w1.z,w2.z,w3.z},{w0.w,w1.w,w2.w,w3.w}};
#pragma unroll
            for (int cc = 0; cc < 4; ++cc) {
                float4 zr = *(float4*)&zt[(c4 * 4 + cc) * 68 + il];
                float zz[4] = {zr.x, zr.y, zr.z, zr.w};
#pragma unroll
                for (int ri = 0; ri < 4; ++ri)
#pragma unroll
                    for (int oi = 0; oi < 4; ++oi)
                        acc[ri][oi] = fmaf(zz[ri], ww[cc][oi], acc[ri][oi]);
            }
        }
#pragma unroll
        for (int ri = 0; ri < 4; ++ri) {
            uint2 pk = make_uint2(
                pack2bf(acc[ri][0] * LOG2E_, acc[ri][1] * LOG2E_),
                pack2bf(acc[ri][2] * LOG2E_, acc[ri][3] * LOG2E_));
            *(uint2*)&qb[((size_t)b * N_ + i0 + il + ri) * CD_ + o0 + og * 4] = pk;
        }
    } else {
        const float* zsrc = zm + (size_t)b * CM_ * N_ + i0;
#pragma unroll
        for (int rep = 0; rep < 4; ++rep) {
            int idx = tid + rep * 256;
            int c = idx >> 4, f = idx & 15;
            *(float4*)&zt[c * 68 + f * 4] = *(const float4*)&zsrc[(size_t)c * N_ + f * 4];
        }
        __syncthreads();
        const float* kr0 = Wk + (size_t)(o0 + og * 4 + 0) * CM_;
        const float* kr1 = Wk + (size_t)(o0 + og * 4 + 1) * CM_;
        const float* kr2 = Wk + (size_t)(o0 + og * 4 + 2) * CM_;
        const float* kr3 = Wk + (size_t)(o0 + og * 4 + 3) * CM_;
        const float* vr0 = Wv + (size_t)(o0 + og * 4 + 0) * CM_;
        const float* vr1 = Wv + (size_t)(o0 + og * 4 + 1) * CM_;
        const float* vr2 = Wv + (size_t)(o0 + og * 4 + 2) * CM_;
        const float* vr3 = Wv + (size_t)(o0 + og * 4 + 3) * CM_;
        float ak[4][4], av[4][4];
#pragma unroll
        for (int oi = 0; oi < 4; ++oi) {
            float bk0 = bk[o0 + og * 4 + oi], bv0 = bv[o0 + og * 4 + oi];
#pragma unroll
            for (int ri = 0; ri < 4; ++ri) { ak[ri][oi] = bk0; av[ri][oi] = bv0; }
        }
        for (int c4 = 0; c4 < 16; ++c4) {
            float4 k0 = *(const float4*)&kr0[c4 * 4];
            float4 k1 = *(const float4*)&kr1[c4 * 4];
            float4 k2 = *(const float4*)&kr2[c4 * 4];
            float4 k3 = *(const float4*)&kr3[c4 * 4];
            float4 v0 = *(const float4*)&vr0[c4 * 4];
            float4 v1 = *(const float4*)&vr1[c4 * 4];
            float4 v2 = *(const float4*)&vr2[c4 * 4];
            float4 v3 = *(const float4*)&vr3[c4 * 4];
            float kk[4][4] = {{k0.x,k1.x,k2.x,k3.x},{k0.y,k1.y,k2.y,k3.y},
                              {k0.z,k1.z,k2.z,k3.z},{k0.w,k1.w,k2.w,k3.w}};
            float vv[4][4] = {{v0.x,v1.x,v2.x,v3.x},{v0.y,v1.y,v2.y,v3.y},
                              {v0.z,v1.z,v2.z,v3.z},{v0.w,v1.w,v2.w,v3.w}};
#pragma unroll
            for (int cc = 0; cc < 4; ++cc) {
                float4 zr = *(float4*)&zt[(c4 * 4 + cc) * 68 + il];
                float zz[4] = {zr.x, zr.y, zr.z, zr.w};
#pragma unroll
                for (int ri = 0; ri < 4; ++ri)
#pragma unroll
                    for (int oi = 0; oi < 4; ++oi) {
                        ak[ri][oi] = fmaf(zz[ri], kk[cc][oi], ak[ri][oi]);
                        av[ri][oi] = fmaf(zz[ri], vv[cc][oi], av[ri][oi]);
                    }
            }
        }
#pragma unroll
        for (int ri = 0; ri < 4; ++ri) {
            uint2 pk = make_uint2(pack2bf(ak[ri][0], ak[ri][1]),
                                  pack2bf(ak[ri][2], ak[ri][3]));
            *(uint2*)&kb[((size_t)b * N_ + i0 + il + ri) * CD_ + o0 + og * 4] = pk;
        }
        const size_t vbase = (size_t)b * CD_ * N_;
#pragma unroll
        for (int oi = 0; oi < 4; ++oi) {
            uint2 pk = make_uint2(pack2bf(av[0][oi], av[1][oi]),
                                  pack2bf(av[2][oi], av[3][oi]));
            *(uint2*)&vb[vbase + (size_t)(o0 + og * 4 + oi) * N_ + i0 + il] = pk;
        }
    }
}

// ---------------- flash + wait-free fan-in combine (fence-free coherence) ----------------
__global__ __launch_bounds__(256, 2)
void flash8(const short* __restrict__ qb, const short* __restrict__ kb,
            const short* __restrict__ vb, __fp16* __restrict__ Op,
            float* __restrict__ ml, unsigned* __restrict__ tilecnt,
            const float* __restrict__ zh, const float* __restrict__ gamma,
            float* __restrict__ out)
{
    __shared__ __align__(16) char smem[65536];
    short* Ks0 = (short*)smem;            // 2 x 8192 shorts
    short* Vs0 = (short*)(smem + 32768);  // 2 x 8192 shorts
    unsigned* flag = (unsigned*)(smem + 65532);  // overlaps Vs[1] (dead after main loop)

    const int tid   = threadIdx.x;
    const int wid   = tid >> 6;
    const int lane  = tid & 63;
    const int m5    = lane & 31;
    const int h     = lane >> 5;
    const int m15   = m5 & 15;
    const int l4r   = lane >> 4;
    const int pc    = (lane & 15) ^ l4r;

    const int vrow = lane >> 3;
    const int vc8  = (lane & 7) ^ (vrow & 7);
    const int voff = vrow * (N_ * 2) + vc8 * 16;

    const int bid = blockIdx.x;
    const int s   = bid % SEG_;
    const int bIt = bid / SEG_;
    const int b   = bIt >= NIT_ ? 1 : 0;
    const int it  = bIt - b * NIT_;
    const int i0  = it * 128;
    const int jbase = s * JSEG_;

    const short* qbp = qb + (size_t)b * N_ * CD_;
    const short* kbp = kb + (size_t)b * N_ * CD_;
    const char*  vstage = (const char*)(vb + (size_t)b * CD_ * N_) + voff;

    const int irow = i0 + wid * 32 + m5;
    bf16x8 qf[8];
#pragma unroll
    for (int kw = 0; kw < 8; ++kw)
        qf[kw] = *(const bf16x8*)&qbp[(size_t)irow * CD_ + kw * 16 + h * 8];

    f32x16 acc[4];
#pragma unroll
    for (int os = 0; os < 4; ++os)
#pragma unroll
        for (int r2 = 0; r2 < 16; ++r2) acc[os][r2] = 0.f;
    float lrun = 0.f;

#pragma unroll
    for (int tt = 0; tt < 4; ++tt) {
        int t = wid * 4 + tt;
        int st = (4 * t) & 15;
        const char* g = (const char*)kbp + (size_t)(jbase + 4 * t + l4r) * 256
                        + ((pc ^ st) << 4);
        __builtin_amdgcn_global_load_lds(
            (const __attribute__((address_space(1))) void*)g,
            (__attribute__((address_space(3))) void*)(Ks0 + t * 512), 16, 0, 0);
    }
#pragma unroll
    for (int tt = 0; tt < 4; ++tt) {
        int t = wid * 4 + tt;
        const char* g = vstage + (size_t)(t * 8) * (N_ * 2) + (size_t)jbase * 2;
        __builtin_amdgcn_global_load_lds(
            (const __attribute__((address_space(1))) void*)g,
            (__attribute__((address_space(3))) void*)(Vs0 + t * 512), 16, 0, 0);
    }
    __syncthreads();

    for (int jti = 0; jti < NJT_; ++jti) {
        const int jt  = jbase + jti * JT_;
        const int cur = jti & 1;
        if (jti + 1 < NJT_) {
            const int jn = jt + JT_;
#pragma unroll
            for (int tt = 0; tt < 4; ++tt) {
                int t = wid * 4 + tt;
                int st = (4 * t) & 15;
                const char* g = (const char*)kbp + (size_t)(jn + 4 * t + l4r) * 256
                                + ((pc ^ st) << 4);
                __builtin_amdgcn_global_load_lds(
                    (const __attribute__((address_space(1))) void*)g,
                    (__attribute__((address_space(3))) void*)(Ks0 + (1 - cur) * 8192 + t * 512), 16, 0, 0);
            }
#pragma unroll
            for (int tt = 0; tt < 4; ++tt) {
                int t = wid * 4 + tt;
                const char* g = vstage + (size_t)(t * 8) * (N_ * 2) + (size_t)jn * 2;
                __builtin_amdgcn_global_load_lds(
                    (const __attribute__((address_space(1))) void*)g,
                    (__attribute__((address_space(3))) void*)(Vs0 + (1 - cur) * 8192 + t * 512), 16, 0, 0);
            }
        }

        unsigned fr[4][4];
#pragma unroll
        for (int jc = 0; jc < 2; ++jc) {
            f32x16 sacc;
#pragma unroll
            for (int r2 = 0; r2 < 16; ++r2) sacc[r2] = -36.067376022224085f;
            __builtin_amdgcn_s_setprio(1);
#pragma unroll
            for (int kw = 0; kw < 8; ++kw) {
                int c16 = (2 * kw + h) ^ m15;
                bf16x8 kf = *(const bf16x8*)&Ks0[cur * 8192 + (jc * 32 + m5) * 128 + c16 * 8];
                sacc = __builtin_amdgcn_mfma_f32_32x32x16_bf16(kf, qf[kw], sacc, 0, 0, 0);
            }
            __builtin_amdgcn_s_setprio(0);
            unsigned pk[8];
#pragma unroll
            for (int p = 0; p < 8; ++p) {
                float e0 = exp2f(sacc[2 * p]);
                float e1 = exp2f(sacc[2 * p + 1]);
                lrun += e0 + e1;
                pk[p] = cvtpk_bf16(e0, e1);
            }
#pragma unroll
            for (int X = 0; X < 2; ++X) {
                auto r0 = __builtin_amdgcn_permlane32_swap(
                              pk[4 * X],     pk[4 * X + 2], false, false);
                auto r1 = __builtin_amdgcn_permlane32_swap(
                              pk[4 * X + 1], pk[4 * X + 3], false, false);
                fr[2 * jc + X][0] = (unsigned)r0[0];
                fr[2 * jc + X][1] = (unsigned)r1[0];
                fr[2 * jc + X][2] = (unsigned)r0[1];
                fr[2 * jc + X][3] = (unsigned)r1[1];
            }
        }
        __builtin_amdgcn_s_setprio(1);
#pragma unroll
        for (int kc = 0; kc < 4; ++kc) {
            union { unsigned u[4]; bf16x8 v; } pf;
#pragma unroll
            for (int u = 0; u < 4; ++u) pf.u[u] = fr[kc][u];
#pragma unroll
            for (int os = 0; os < 4; ++os) {
                int o = os * 32 + m5;
                int q = (kc * 2 + h) ^ (m5 & 7);
                bf16x8 vf = *(const bf16x8*)&Vs0[cur * 8192 + o * 64 + q * 8];
                acc[os] = __builtin_amdgcn_mfma_f32_32x32x16_bf16(vf, pf.v, acc[os], 0, 0, 0);
            }
        }
        __builtin_amdgcn_s_setprio(0);
        __syncthreads();
    }

    float lt = lrun + __shfl_xor(lrun, 32);
    if (h == 0)
        st_agent_f(&ml[((size_t)bIt * SEG_ + s) * 128 + wid * 32 + m5], lt);
    const float linv = 1.0f / lt;

    // epilogue: normalized partials -> f16 Op (agent write-through, no fences)
    float* Of = (float*)smem;
    __fp16* opb = Op + ((size_t)bIt * SEG_ + s) * (128 * CD_);
#pragma unroll
    for (int r = 0; r < 2; ++r) {
        __syncthreads();
        if ((wid >> 1) == r) {
            const int il_ = (wid & 1) * 32 + m5;
#pragma unroll
            for (int os = 0; os < 4; ++os) {
#pragma unroll
                for (int g = 0; g < 4; ++g) {
                    int q = os * 8 + g * 2 + h;
                    int p = q ^ m5;
                    *(float4*)&Of[il_ * 128 + p * 4] =
                        make_float4(acc[os][4 * g] * linv, acc[os][4 * g + 1] * linv,
                                    acc[os][4 * g + 2] * linv, acc[os][4 * g + 3] * linv);
                }
            }
        }
        __syncthreads();
#pragma unroll
        for (int u = 0; u < 8; ++u) {
            int G = u * 256 + tid;
            int i = G >> 5;
            int q = tid & 31;
            int p = q ^ (i & 31);
            float4 t = *(float4*)&Of[i * 128 + p * 4];
            union { f16x2 h2[2]; u64 u8; } cv;
            cv.h2[0] = __builtin_amdgcn_cvt_pkrtz(t.x, t.y);
            cv.h2[1] = __builtin_amdgcn_cvt_pkrtz(t.z, t.w);
            st_agent((u64*)&opb[(size_t)r * 64 * CD_ + (size_t)G * 4], cv.u8);
        }
    }

    // -------- wait-free fan-in: last of the 5 segment-blocks combines --------
    // __syncthreads' vmcnt(0) drain => all sc1 stores are at LLC before the atomic.
    __syncthreads();
    if (tid == 0) *flag = atomicAdd(&tilecnt[bIt], 1u);   // device-scope RMW, relaxed
    __syncthreads();
    if (*flag == SEG_ - 1) {
        float* T = (float*)smem;                           // [o][i(64)+pad], 34.8 KB
        const float g = gamma[0];
        const __fp16* opt = Op + (size_t)bIt * SEG_ * (128 * CD_);
#pragma unroll
        for (int r = 0; r < 2; ++r) {
            const int i   = tid >> 2;                      // 0..63
            const int row = r * 64 + i;
            float l[SEG_], den = 0.f;
#pragma unroll
            for (int s2 = 0; s2 < SEG_; ++s2) {
                l[s2] = ld_agent_f(&ml[((size_t)bIt * SEG_ + s2) * 128 + row]);
                den += l[s2];
            }
            const float gd = g / den;
            float w[SEG_];
#pragma unroll
            for (int s2 = 0; s2 < SEG_; ++s2) w[s2] = l[s2] * gd;
            const int oc = (tid & 3) * 32;
#pragma unroll
            for (int och = 0; och < 8; ++och) {
                int o4 = oc + och * 4;
                float ax = 0.f, ay = 0.f, az = 0.f, aw = 0.f;
#pragma unroll
                for (int s2 = 0; s2 < SEG_; ++s2) {
                    union { u64 u8; f16x2 h2[2]; } raw;
                    raw.u8 = ld_agent((const u64*)&opt[((size_t)s2 * 128 + row) * CD_ + o4]);
                    ax = fmaf((float)raw.h2[0][0], w[s2], ax);
                    ay = fmaf((float)raw.h2[0][1], w[s2], ay);
                    az = fmaf((float)raw.h2[1][0], w[s2], az);
                    aw = fmaf((float)raw.h2[1][1], w[s2], aw);
                }
                T[(o4 + 0) * 68 + i] = ax;
                T[(o4 + 1) * 68 + i] = ay;
                T[(o4 + 2) * 68 + i] = az;
                T[(o4 + 3) * 68 + i] = aw;
            }
            __syncthreads();
            {
                const int o = tid >> 1, ih = (tid & 1) * 32;
                const size_t gbase = ((size_t)b * CD_ + o) * N_ + i0 + r * 64 + ih;
#pragma unroll
                for (int rr = 0; rr < 8; ++rr) {
                    float4 t  = *(float4*)&T[o * 68 + ih + rr * 4];
                    float4 z4 = *(const float4*)&zh[gbase + rr * 4];
                    *(float4*)&out[gbase + rr * 4] =
                        make_float4(t.x + z4.x, t.y + z4.y, t.z + z4.z, t.w + z4.w);
                }
            }
            __syncthreads();
        }
    }
}

extern "C" void kernel_launch(void* const* d_in, const int* in_sizes, int n_in,
                              void* d_out, int out_size, void* d_ws, size_t ws_size,
                              hipStream_t stream) {
    const float* z_hsi = (const float*)d_in[0];
    const float* z_msi = (const float*)d_in[1];
    const float* Wq    = (const float*)d_in[2];
    const float* bq    = (const float*)d_in[3];
    const float* Wk    = (const float*)d_in[4];
    const float* bk    = (const float*)d_in[5];
    const float* Wv    = (const float*)d_in[6];
    const float* bv    = (const float*)d_in[7];
    const float* gamma = (const float*)d_in[8];
    float* out = (float*)d_out;

    const size_t nqb = (size_t)B_ * N_ * CD_;
    short* qb = (short*)d_ws;
    short* kb = qb + nqb;
    short* vb = kb + nqb;
    __fp16* Op = (__fp16*)(vb + nqb);                              // 16.4 MB
    float* ml = (float*)(Op + (size_t)100 * SEG_ * 128 * CD_);     // 256 KB
    unsigned* tilecnt = (unsigned*)(ml + (size_t)100 * SEG_ * 128);

    proj2<<<dim3(800), dim3(256), 0, stream>>>(z_hsi, z_msi, Wq, bq, Wk, bk, Wv, bv,
                                               qb, kb, vb, tilecnt);
    flash8<<<dim3(100 * SEG_), dim3(256), 0, stream>>>(qb, kb, vb, Op, ml, tilecnt,
                                                       z_hsi, gamma, out);
}